// Round 10
// baseline (681.242 us; speedup 1.0000x reference)
//
#include <hip/hip_runtime.h>
#include <hip/hip_bf16.h>
#include <float.h>
#include <math.h>

#define NB 32
#define NS 4096
#define NE 1024
#define ND 1024
#define NA 512

typedef __attribute__((ext_vector_type(4))) float f32x4;
typedef __attribute__((ext_vector_type(8))) short short8;

static __device__ __forceinline__ ushort f2bf(float f){
    union { float f; unsigned int u; } x; x.f = f;
    unsigned int u = x.u + 0x7fffu + ((x.u >> 16) & 1u);
    return (ushort)(u >> 16);
}

static __device__ __forceinline__ float tanh_fast(float x){
    float e = __expf(2.f * x);
    return 1.f - 2.f / (e + 1.f);
}

// ---- K1a: W_h (1024x512 f32) -> WTf bf16 in MFMA-fragment order ----
// WTf[((s*32 + ng)*64 + lane)*8 + e]  (s = k-slice of 32, ng = n-frag of 16 cols)
//   = Wh[k = s*32 + (lane>>4)*8 + e][col = ng*16 + (lane&15)]
__global__ __launch_bounds__(256) void k_prep_wtf(const float* __restrict__ Wh,
                                                  ushort* __restrict__ WTf){
    int i = blockIdx.x * 256 + threadIdx.x;   // 524288 outputs
    int e = i & 7;
    int lane = (i >> 3) & 63;
    int ng = (i >> 9) & 31;
    int s = i >> 14;
    int k = s * 32 + (lane >> 4) * 8 + e;
    int col = ng * 16 + (lane & 15);
    WTf[i] = f2bf(Wh[k * NA + col]);
}

// ---- K1b: proj_dec partials ----
__global__ __launch_bounds__(512) void k_projdec(const float* __restrict__ dec,
                                                 const float* __restrict__ Ws,
                                                 float* __restrict__ pdp){
    int b = blockIdx.x >> 2, kc = blockIdx.x & 3;
    int a = threadIdx.x;
    const float* dp = dec + b * ND + kc * 256;
    const float* wp = Ws + (size_t)(kc * 256) * NA + a;
    float acc = 0.f;
    #pragma unroll 4
    for (int k = 0; k < 256; k++) acc += dp[k] * wp[(size_t)k * NA];
    pdp[(kc * NB + b) * NA + a] = acc;
}

// ---- K2: fused scores GEMM — NO LDS, NO BARRIERS in the K-loop. ----
// BM=128, BN=128 (bn quarter), BK=32, 4 waves (2x2), wave-tile 64x64.
// A-frags loaded DIRECTLY from row-major f32 E (2 x 16B per frag per lane,
// lane=(l15,grp): row=l15, k=grp*8+e), converted in-register to bf16.
// B-frags stream from frag-ordered WTf (L2). Waves fully independent.
__global__ __launch_bounds__(256, 3) void k_scores(const float* __restrict__ E,
                                                   const ushort* __restrict__ WTf,
                                                   const float* __restrict__ pdp,
                                                   const float* __restrict__ v,
                                                   float* __restrict__ scrp){
    const int t = threadIdx.x;
    const int lane = t & 63, w = t >> 6;
    const int l15 = lane & 15, grp = lane >> 4;
    const int wm = w >> 1, wn = w & 1;

    // XCD-major mapping: 4096 blocks; 4 bn-quarters of one m-tile adjacent.
    const int bid = blockIdx.x;
    const int xcd = bid & 7, slot = bid >> 3;     // 512 slots per XCD
    const int mblk = xcd * 128 + (slot >> 2);     // 0..1023
    const int bn = slot & 3;                      // N-quarter
    const int m0 = mblk << 7;                     // 128-row base
    const int b = mblk >> 5;                      // batch

    __shared__ float sc[128][2];

    f32x4 acc[4][4];
    f32x4 zero; zero[0]=0.f; zero[1]=0.f; zero[2]=0.f; zero[3]=0.f;
    #pragma unroll
    for (int m = 0; m < 4; m++)
        #pragma unroll
        for (int n = 0; n < 4; n++) acc[m][n] = zero;

    // per-m A base pointers (this lane's row, this lane's k-octet)
    const float* am[4];
    #pragma unroll
    for (int m = 0; m < 4; m++)
        am[m] = E + (size_t)(m0 + wm * 64 + m * 16 + l15) * NE + grp * 8;

    // B-frag base: ng = bn*8 + wn*4 + n; slice s = it at +it*16384 ushorts
    const ushort* wtf0 = WTf + ((size_t)(bn * 8 + wn * 4) * 64 + lane) * 8;

    for (int it = 0; it < 32; ++it){
        // B-frags (L2-hot)
        short8 wt[4];
        const ushort* wp = wtf0 + (size_t)it * 16384;
        #pragma unroll
        for (int n = 0; n < 4; n++) wt[n] = *(const short8*)(wp + n * 512);
        // A-frags direct from f32 E
        f32x4 a0[4], a1[4];
        #pragma unroll
        for (int m = 0; m < 4; m++){
            const float* p = am[m] + it * 32;
            a0[m] = *(const f32x4*)p;
            a1[m] = *(const f32x4*)(p + 4);
        }
        // cvt + MFMA (compiler fine-grains the vmcnt waits per m)
        #pragma unroll
        for (int m = 0; m < 4; m++){
            short8 af;
            #pragma unroll
            for (int e = 0; e < 4; e++){
                af[e]     = (short)__builtin_bit_cast(ushort, __float2bfloat16(a0[m][e]));
                af[e + 4] = (short)__builtin_bit_cast(ushort, __float2bfloat16(a1[m][e]));
            }
            #pragma unroll
            for (int n = 0; n < 4; n++)
                acc[m][n] = __builtin_amdgcn_mfma_f32_16x16x32_bf16(af, wt[n], acc[m][n], 0, 0, 0);
        }
    }

    // epilogue: +proj_dec, fast-tanh, v-dot, reduce over this block's 128 cols
    float pdc[4], vc[4];
    #pragma unroll
    for (int n = 0; n < 4; n++){
        int c = bn * 128 + wn * 64 + n * 16 + l15;
        float p = 0.f;
        #pragma unroll
        for (int kc = 0; kc < 4; kc++) p += pdp[(kc * NB + b) * NA + c];
        pdc[n] = p;
        vc[n] = v[c];
    }
    #pragma unroll
    for (int m = 0; m < 4; m++){
        #pragma unroll
        for (int j = 0; j < 4; j++){
            float s = 0.f;
            #pragma unroll
            for (int n = 0; n < 4; n++) s += tanh_fast(acc[m][n][j] + pdc[n]) * vc[n];
            s += __shfl_xor(s, 1);
            s += __shfl_xor(s, 2);
            s += __shfl_xor(s, 4);
            s += __shfl_xor(s, 8);
            if (l15 == 0) sc[wm * 64 + m * 16 + grp * 4 + j][wn] = s;
        }
    }
    __syncthreads();
    if (t < 128)
        scrp[(size_t)bn * (NB * NS) + m0 + t] = sc[t][0] + sc[t][1];
}

// ---- K3: masked softmax; sums the four N-quarter score partials ----
__global__ __launch_bounds__(256) void k_softmax(const float* __restrict__ scrp,
                                                 const int* __restrict__ mask,
                                                 float* __restrict__ weights){
    int b = blockIdx.x, t = threadIdx.x;
    __shared__ float red[8];
    float vals[16];
    float mx = -FLT_MAX;
    #pragma unroll
    for (int i = 0; i < 16; i++){
        int s = i * 256 + t;
        float x = scrp[b * NS + s]
                + scrp[(size_t)(NB * NS) + b * NS + s]
                + scrp[2 * (size_t)(NB * NS) + b * NS + s]
                + scrp[3 * (size_t)(NB * NS) + b * NS + s];
        x = (mask[b * NS + s] != 0) ? x : -FLT_MAX;
        vals[i] = x;
        mx = fmaxf(mx, x);
    }
    #pragma unroll
    for (int off = 32; off; off >>= 1) mx = fmaxf(mx, __shfl_xor(mx, off));
    int wv = t >> 6;
    if ((t & 63) == 0) red[wv] = mx;
    __syncthreads();
    mx = fmaxf(fmaxf(red[0], red[1]), fmaxf(red[2], red[3]));
    float sum = 0.f;
    #pragma unroll
    for (int i = 0; i < 16; i++){ vals[i] = __expf(vals[i] - mx); sum += vals[i]; }
    #pragma unroll
    for (int off = 32; off; off >>= 1) sum += __shfl_xor(sum, off);
    if ((t & 63) == 0) red[4 + wv] = sum;
    __syncthreads();
    sum = red[4] + red[5] + red[6] + red[7];
    float inv = 1.f / sum;
    #pragma unroll
    for (int i = 0; i < 16; i++) weights[b * NS + i * 256 + t] = vals[i] * inv;
}

// ---- K4: context partials over S-chunks ----
__global__ __launch_bounds__(1024) void k_context(const float* __restrict__ E,
                                                  const float* __restrict__ weights,
                                                  float* __restrict__ part){
    int b = blockIdx.x >> 3, ch = blockIdx.x & 7;
    int t = threadIdx.x;
    int h = t >> 8, tg = t & 255;
    __shared__ float wsm[512];
    __shared__ __align__(16) f32x4 red[4][256];
    if (t < 512) wsm[t] = weights[b * NS + ch * 512 + t];
    __syncthreads();
    const f32x4* Ep = (const f32x4*)(E + ((size_t)b * NS + ch * 512 + h * 128) * NE) + tg;
    f32x4 acc; acc[0]=0.f; acc[1]=0.f; acc[2]=0.f; acc[3]=0.f;
    #pragma unroll 4
    for (int s = 0; s < 128; s++){
        f32x4 e = Ep[(size_t)s * 256];
        float w = wsm[h * 128 + s];
        acc[0] += w * e[0]; acc[1] += w * e[1];
        acc[2] += w * e[2]; acc[3] += w * e[3];
    }
    red[h][tg] = acc;
    __syncthreads();
    if (h == 0){
        f32x4 a0 = red[0][tg], a1 = red[1][tg], a2 = red[2][tg], a3 = red[3][tg];
        f32x4 s;
        s[0] = a0[0]+a1[0]+a2[0]+a3[0];
        s[1] = a0[1]+a1[1]+a2[1]+a3[1];
        s[2] = a0[2]+a1[2]+a2[2]+a3[2];
        s[3] = a0[3]+a1[3]+a2[3]+a3[3];
        *(f32x4*)(part + ((size_t)(b * 8 + ch)) * NE + tg * 4) = s;
    }
}

// ---- K5: reduce context partials ----
__global__ __launch_bounds__(256) void k_reduce_ctx(const float* __restrict__ part,
                                                    float* __restrict__ ctx){
    int i = blockIdx.x * 256 + threadIdx.x;  // 32768
    int b = i >> 10, e = i & 1023;
    float s = 0.f;
    #pragma unroll
    for (int ch = 0; ch < 8; ch++) s += part[((size_t)(b * 8 + ch)) * NE + e];
    ctx[i] = s;
}

extern "C" void kernel_launch(void* const* d_in, const int* in_sizes, int n_in,
                              void* d_out, int out_size, void* d_ws, size_t ws_size,
                              hipStream_t stream){
    const float* dec  = (const float*)d_in[0];
    const float* E    = (const float*)d_in[1];
    const int*   mask = (const int*)d_in[2];
    const float* Wh   = (const float*)d_in[3];
    const float* Ws   = (const float*)d_in[4];
    const float* v    = (const float*)d_in[5];
    float* ctx = (float*)d_out;               // (32,1024)
    float* weights = (float*)d_out + NB * NE; // (32,4096)

    char* ws = (char*)d_ws;
    ushort* WTf  = (ushort*)ws;                                     // 1 MB (frag-order W_h)
    float*  part = (float*)ws;                                      // 1 MB ctx partials (after k_scores)
    float*  pdp  = (float*)(ws + (1 << 20));                        // 256 KB proj_dec partials
    float*  scrp = (float*)(ws + (1 << 20) + (256 << 10));          // 2 MB score partials (4 quarters)

    k_prep_wtf<<<2048, 256, 0, stream>>>(Wh, WTf);
    k_projdec<<<128, 512, 0, stream>>>(dec, Ws, pdp);
    k_scores<<<4096, 256, 0, stream>>>(E, WTf, pdp, v, scrp);
    k_softmax<<<32, 256, 0, stream>>>(scrp, mask, weights);
    k_context<<<256, 1024, 0, stream>>>(E, weights, part);
    k_reduce_ctx<<<128, 256, 0, stream>>>(part, ctx);
}

// Round 11
// 540.667 us; speedup vs baseline: 1.2600x; 1.2600x over previous
//
#include <hip/hip_runtime.h>
#include <hip/hip_bf16.h>
#include <float.h>
#include <math.h>

#define NB 32
#define NS 4096
#define NE 1024
#define ND 1024
#define NA 512

typedef __attribute__((ext_vector_type(4))) float f32x4;
typedef __attribute__((ext_vector_type(8))) short short8;

static __device__ __forceinline__ ushort f2bf(float f){
    union { float f; unsigned int u; } x; x.f = f;
    unsigned int u = x.u + 0x7fffu + ((x.u >> 16) & 1u);
    return (ushort)(u >> 16);
}

static __device__ __forceinline__ float tanh_fast(float x){
    float e = __expf(2.f * x);
    return 1.f - 2.f / (e + 1.f);
}

// ---- K1a: W_h (1024x512 f32) -> WTf bf16 in MFMA-fragment order ----
// WTf[((s*32 + ng)*64 + lane)*8 + e]  (s = k-slice of 32, ng = n-frag of 16 cols)
//   = Wh[k = s*32 + (lane>>4)*8 + e][col = ng*16 + (lane&15)]
__global__ __launch_bounds__(256) void k_prep_wtf(const float* __restrict__ Wh,
                                                  ushort* __restrict__ WTf){
    int i = blockIdx.x * 256 + threadIdx.x;   // 524288 outputs
    int e = i & 7;
    int lane = (i >> 3) & 63;
    int ng = (i >> 9) & 31;
    int s = i >> 14;
    int k = s * 32 + (lane >> 4) * 8 + e;
    int col = ng * 16 + (lane & 15);
    WTf[i] = f2bf(Wh[k * NA + col]);
}

// ---- K1b: proj_dec partials ----
__global__ __launch_bounds__(512) void k_projdec(const float* __restrict__ dec,
                                                 const float* __restrict__ Ws,
                                                 float* __restrict__ pdp){
    int b = blockIdx.x >> 2, kc = blockIdx.x & 3;
    int a = threadIdx.x;
    const float* dp = dec + b * ND + kc * 256;
    const float* wp = Ws + (size_t)(kc * 256) * NA + a;
    float acc = 0.f;
    #pragma unroll 4
    for (int k = 0; k < 256; k++) acc += dp[k] * wp[(size_t)k * NA];
    pdp[(kc * NB + b) * NA + a] = acc;
}

// ---- K2: fused scores GEMM, FULL-K tile (BK=1024): stage once, ONE barrier,
// then 32 K-slices of pure {wt L2 loads + 1 ds_read + 4 MFMA} with no barriers.
// BM=32, BN=128 (bn quarter), 4 waves (2m x 2n), wave-tile 16x64, acc = 16 AGPR.
// 64KB LDS -> 2 blocks/CU: one stages (HBM) while the other computes.
__global__ __launch_bounds__(256, 2) void k_scores(const float* __restrict__ E,
                                                   const ushort* __restrict__ WTf,
                                                   const float* __restrict__ pdp,
                                                   const float* __restrict__ v,
                                                   float* __restrict__ scrp){
    const int t = threadIdx.x;
    const int lane = t & 63, w = t >> 6;
    const int l15 = lane & 15, grp = lane >> 4;
    const int wm = w >> 1, wn = w & 1;

    // XCD-major mapping: 16384 blocks; 4 bn-quarters of one m-tile adjacent.
    const int bid = blockIdx.x;
    const int xcd = bid & 7, slot = bid >> 3;     // 2048 slots per XCD
    const int mblk = xcd * 512 + (slot >> 2);     // 0..4095
    const int bn = slot & 3;                      // N-quarter
    const int m0 = mblk << 5;                     // 32-row base
    const int b = mblk >> 7;                      // batch

    __shared__ __align__(16) ushort ebf[32 * 1024];  // 64 KB bf16 tile (swizzled)
    __shared__ float sc[32][2];

    // ---- stage: 32 rows x 1024 f32 -> bf16 LDS, once ----
    // thread: row = t>>3, q = t&7; chunk c = j*8+q (8 floats = one short8)
    {
        const int srow = t >> 3, q = t & 7;
        const float* gsrc = E + (size_t)(m0 + srow) * NE;
        char* lbase = (char*)ebf + srow * 2048;
        const unsigned swz = (unsigned)((srow & 7) << 4);
        #pragma unroll
        for (int j = 0; j < 16; ++j){
            const int c = j * 8 + q;
            const f32x4* p = (const f32x4*)(gsrc + c * 8);
            f32x4 lo = p[0], hi = p[1];
            short8 h;
            #pragma unroll
            for (int e = 0; e < 4; e++){
                h[e]     = (short)__builtin_bit_cast(ushort, __float2bfloat16(lo[e]));
                h[e + 4] = (short)__builtin_bit_cast(ushort, __float2bfloat16(hi[e]));
            }
            *(short8*)(lbase + (((unsigned)(c * 16)) ^ swz)) = h;
        }
    }
    __syncthreads();

    // ---- compute: 32 K-slices, barrier-free ----
    f32x4 acc[4];
    f32x4 zero; zero[0]=0.f; zero[1]=0.f; zero[2]=0.f; zero[3]=0.f;
    #pragma unroll
    for (int n = 0; n < 4; n++) acc[n] = zero;

    const ushort* wtf0 = WTf + ((size_t)(bn * 8 + wn * 4) * 64 + lane) * 8;
    const int arow = wm * 16 + l15;
    const char* abase = (const char*)ebf + arow * 2048;
    const unsigned aswz = (unsigned)((arow & 7) << 4);

    #pragma unroll 4
    for (int s = 0; s < 32; ++s){
        short8 wt[4];
        const ushort* wp = wtf0 + (size_t)s * 16384;
        #pragma unroll
        for (int n = 0; n < 4; n++) wt[n] = *(const short8*)(wp + n * 512);
        short8 af = *(const short8*)(abase + (((unsigned)((s * 4 + grp) * 16)) ^ aswz));
        #pragma unroll
        for (int n = 0; n < 4; n++)
            acc[n] = __builtin_amdgcn_mfma_f32_16x16x32_bf16(af, wt[n], acc[n], 0, 0, 0);
    }

    // ---- epilogue: +proj_dec, fast-tanh, v-dot, reduce over 128 quarter-cols ----
    float pdc[4], vc[4];
    #pragma unroll
    for (int n = 0; n < 4; n++){
        int c = bn * 128 + wn * 64 + n * 16 + l15;
        float p = 0.f;
        #pragma unroll
        for (int kc = 0; kc < 4; kc++) p += pdp[(kc * NB + b) * NA + c];
        pdc[n] = p;
        vc[n] = v[c];
    }
    #pragma unroll
    for (int j = 0; j < 4; j++){
        float s = 0.f;
        #pragma unroll
        for (int n = 0; n < 4; n++) s += tanh_fast(acc[n][j] + pdc[n]) * vc[n];
        s += __shfl_xor(s, 1);
        s += __shfl_xor(s, 2);
        s += __shfl_xor(s, 4);
        s += __shfl_xor(s, 8);
        if (l15 == 0) sc[wm * 16 + grp * 4 + j][wn] = s;
    }
    __syncthreads();
    if (t < 32)
        scrp[(size_t)bn * (NB * NS) + m0 + t] = sc[t][0] + sc[t][1];
}

// ---- K3: masked softmax; sums the four N-quarter score partials ----
__global__ __launch_bounds__(256) void k_softmax(const float* __restrict__ scrp,
                                                 const int* __restrict__ mask,
                                                 float* __restrict__ weights){
    int b = blockIdx.x, t = threadIdx.x;
    __shared__ float red[8];
    float vals[16];
    float mx = -FLT_MAX;
    #pragma unroll
    for (int i = 0; i < 16; i++){
        int s = i * 256 + t;
        float x = scrp[b * NS + s]
                + scrp[(size_t)(NB * NS) + b * NS + s]
                + scrp[2 * (size_t)(NB * NS) + b * NS + s]
                + scrp[3 * (size_t)(NB * NS) + b * NS + s];
        x = (mask[b * NS + s] != 0) ? x : -FLT_MAX;
        vals[i] = x;
        mx = fmaxf(mx, x);
    }
    #pragma unroll
    for (int off = 32; off; off >>= 1) mx = fmaxf(mx, __shfl_xor(mx, off));
    int wv = t >> 6;
    if ((t & 63) == 0) red[wv] = mx;
    __syncthreads();
    mx = fmaxf(fmaxf(red[0], red[1]), fmaxf(red[2], red[3]));
    float sum = 0.f;
    #pragma unroll
    for (int i = 0; i < 16; i++){ vals[i] = __expf(vals[i] - mx); sum += vals[i]; }
    #pragma unroll
    for (int off = 32; off; off >>= 1) sum += __shfl_xor(sum, off);
    if ((t & 63) == 0) red[4 + wv] = sum;
    __syncthreads();
    sum = red[4] + red[5] + red[6] + red[7];
    float inv = 1.f / sum;
    #pragma unroll
    for (int i = 0; i < 16; i++) weights[b * NS + i * 256 + t] = vals[i] * inv;
}

// ---- K4: context partials over S-chunks ----
__global__ __launch_bounds__(1024) void k_context(const float* __restrict__ E,
                                                  const float* __restrict__ weights,
                                                  float* __restrict__ part){
    int b = blockIdx.x >> 3, ch = blockIdx.x & 7;
    int t = threadIdx.x;
    int h = t >> 8, tg = t & 255;
    __shared__ float wsm[512];
    __shared__ __align__(16) f32x4 red[4][256];
    if (t < 512) wsm[t] = weights[b * NS + ch * 512 + t];
    __syncthreads();
    const f32x4* Ep = (const f32x4*)(E + ((size_t)b * NS + ch * 512 + h * 128) * NE) + tg;
    f32x4 acc; acc[0]=0.f; acc[1]=0.f; acc[2]=0.f; acc[3]=0.f;
    #pragma unroll 4
    for (int s = 0; s < 128; s++){
        f32x4 e = Ep[(size_t)s * 256];
        float w = wsm[h * 128 + s];
        acc[0] += w * e[0]; acc[1] += w * e[1];
        acc[2] += w * e[2]; acc[3] += w * e[3];
    }
    red[h][tg] = acc;
    __syncthreads();
    if (h == 0){
        f32x4 a0 = red[0][tg], a1 = red[1][tg], a2 = red[2][tg], a3 = red[3][tg];
        f32x4 s;
        s[0] = a0[0]+a1[0]+a2[0]+a3[0];
        s[1] = a0[1]+a1[1]+a2[1]+a3[1];
        s[2] = a0[2]+a1[2]+a2[2]+a3[2];
        s[3] = a0[3]+a1[3]+a2[3]+a3[3];
        *(f32x4*)(part + ((size_t)(b * 8 + ch)) * NE + tg * 4) = s;
    }
}

// ---- K5: reduce context partials ----
__global__ __launch_bounds__(256) void k_reduce_ctx(const float* __restrict__ part,
                                                    float* __restrict__ ctx){
    int i = blockIdx.x * 256 + threadIdx.x;  // 32768
    int b = i >> 10, e = i & 1023;
    float s = 0.f;
    #pragma unroll
    for (int ch = 0; ch < 8; ch++) s += part[((size_t)(b * 8 + ch)) * NE + e];
    ctx[i] = s;
}

extern "C" void kernel_launch(void* const* d_in, const int* in_sizes, int n_in,
                              void* d_out, int out_size, void* d_ws, size_t ws_size,
                              hipStream_t stream){
    const float* dec  = (const float*)d_in[0];
    const float* E    = (const float*)d_in[1];
    const int*   mask = (const int*)d_in[2];
    const float* Wh   = (const float*)d_in[3];
    const float* Ws   = (const float*)d_in[4];
    const float* v    = (const float*)d_in[5];
    float* ctx = (float*)d_out;               // (32,1024)
    float* weights = (float*)d_out + NB * NE; // (32,4096)

    char* ws = (char*)d_ws;
    ushort* WTf  = (ushort*)ws;                                     // 1 MB (frag-order W_h)
    float*  part = (float*)ws;                                      // 1 MB ctx partials (after k_scores)
    float*  pdp  = (float*)(ws + (1 << 20));                        // 256 KB proj_dec partials
    float*  scrp = (float*)(ws + (1 << 20) + (256 << 10));          // 2 MB score partials (4 quarters)

    k_prep_wtf<<<2048, 256, 0, stream>>>(Wh, WTf);
    k_projdec<<<128, 512, 0, stream>>>(dec, Ws, pdp);
    k_scores<<<16384, 256, 0, stream>>>(E, WTf, pdp, v, scrp);
    k_softmax<<<32, 256, 0, stream>>>(scrp, mask, weights);
    k_context<<<256, 1024, 0, stream>>>(E, weights, part);
    k_reduce_ctx<<<128, 256, 0, stream>>>(part, ctx);
}

// Round 12
// 393.045 us; speedup vs baseline: 1.7332x; 1.3756x over previous
//
#include <hip/hip_runtime.h>
#include <hip/hip_bf16.h>
#include <float.h>
#include <math.h>

#define NB 32
#define NS 4096
#define NE 1024
#define ND 1024
#define NA 512

typedef __attribute__((ext_vector_type(4))) float f32x4;
typedef __attribute__((ext_vector_type(8))) short short8;
typedef __attribute__((address_space(3))) char lds_char_t;
typedef __attribute__((address_space(1))) const char g_char_t;

static __device__ __forceinline__ ushort f2bf(float f){
    union { float f; unsigned int u; } x; x.f = f;
    unsigned int u = x.u + 0x7fffu + ((x.u >> 16) & 1u);
    return (ushort)(u >> 16);
}

static __device__ __forceinline__ float tanh_fast(float x){
    float e = __expf(2.f * x);
    return 1.f - 2.f / (e + 1.f);
}

// ---- K1a: W_h (1024x512 f32) -> WTf bf16 in MFMA-fragment order ----
// WTf[((s*32 + ng)*64 + lane)*8 + e]  (s = k-slice of 32, ng = n-frag of 16 cols)
//   = Wh[k = s*32 + (lane>>4)*8 + e][col = ng*16 + (lane&15)]
__global__ __launch_bounds__(256) void k_prep_wtf(const float* __restrict__ Wh,
                                                  ushort* __restrict__ WTf){
    int i = blockIdx.x * 256 + threadIdx.x;   // 524288 outputs
    int e = i & 7;
    int lane = (i >> 3) & 63;
    int ng = (i >> 9) & 31;
    int s = i >> 14;
    int k = s * 32 + (lane >> 4) * 8 + e;
    int col = ng * 16 + (lane & 15);
    WTf[i] = f2bf(Wh[k * NA + col]);
}

// ---- K1b: proj_dec partials ----
__global__ __launch_bounds__(512) void k_projdec(const float* __restrict__ dec,
                                                 const float* __restrict__ Ws,
                                                 float* __restrict__ pdp){
    int b = blockIdx.x >> 2, kc = blockIdx.x & 3;
    int a = threadIdx.x;
    const float* dp = dec + b * ND + kc * 256;
    const float* wp = Ws + (size_t)(kc * 256) * NA + a;
    float acc = 0.f;
    #pragma unroll 4
    for (int k = 0; k < 256; k++) acc += dp[k] * wp[(size_t)k * NA];
    pdp[(kc * NB + b) * NA + a] = acc;
}

// ---- K2: fused scores GEMM. BM=128, BN=128 (bn quarter), BK=32, 4 waves (2x2).
// E staged f32 via global_load_lds into a 3-buffer LDS ring (counted vmcnt,
// never 0 in the loop). Source pre-swizzled (q ^ (row&7)), linear LDS dest,
// swizzled ds_read. wt one-iter register prefetch (ping-pong). 3 blocks/CU.
__global__ __launch_bounds__(256, 3) void k_scores(const float* __restrict__ E,
                                                   const ushort* __restrict__ WTf,
                                                   const float* __restrict__ pdp,
                                                   const float* __restrict__ v,
                                                   float* __restrict__ scrp){
    const int t = threadIdx.x;
    const int lane = t & 63, w = t >> 6;
    const int l15 = lane & 15, grp = lane >> 4;
    const int wm = w >> 1, wn = w & 1;

    // XCD-major mapping: 4096 blocks; 4 bn-quarters of one m-tile adjacent.
    const int bid = blockIdx.x;
    const int xcd = bid & 7, slot = bid >> 3;     // 512 slots per XCD
    const int mblk = xcd * 128 + (slot >> 2);     // 0..1023
    const int bn = slot & 3;                      // N-quarter
    const int m0 = mblk << 7;                     // 128-row base
    const int b = mblk >> 5;                      // batch

    __shared__ __align__(16) float ebf[3][128 * 32];  // 3 x 16KB f32 ring (DMA dest)
    __shared__ float sc[128][2];

    // DMA: chunk c = w*256 + i*64 + lane covers (row = c>>3, lds-slot qq = c&7).
    // Source chunk q_src = qq ^ (row&7)  (T21 involution; read side applies same XOR).
    // Per instr: 8 rows x 128B contiguous segments -> fully coalesced.
    auto dma = [&](int it){
        float* bufp = &ebf[it % 3][0];
        #pragma unroll
        for (int i = 0; i < 4; ++i){
            const int c = w * 256 + i * 64 + lane;
            const int row = c >> 3, qq = c & 7;
            const int qs = qq ^ (row & 7);
            const float* src = E + (size_t)(m0 + row) * NE + it * 32 + qs * 4;
            lds_char_t* dst = (lds_char_t*)((char*)bufp + c * 16);
            __builtin_amdgcn_global_load_lds((g_char_t*)src, dst, 16, 0, 0);
        }
    };

    f32x4 acc[4][4];
    f32x4 zero; zero[0]=0.f; zero[1]=0.f; zero[2]=0.f; zero[3]=0.f;
    #pragma unroll
    for (int m = 0; m < 4; m++)
        #pragma unroll
        for (int n = 0; n < 4; n++) acc[m][n] = zero;

    // B-frag base: ng = bn*8 + wn*4 + n; slice s = it at +it*16384 ushorts
    const ushort* wtf0 = WTf + ((size_t)(bn * 8 + wn * 4) * 64 + lane) * 8;
    short8 wtA[4], wtB[4];

    // per-m A row constants
    int arow[4]; unsigned aqA[4];
    #pragma unroll
    for (int m = 0; m < 4; m++){
        arow[m] = wm * 64 + m * 16 + l15;
        aqA[m] = (unsigned)((grp * 2) ^ (arow[m] & 7));
    }

    // prologue: DMA(0), DMA(1), wt(0); wait DMA(0) only (vmcnt(8)); barrier.
    dma(0);
    dma(1);
    #pragma unroll
    for (int n = 0; n < 4; n++) wtA[n] = *(const short8*)(wtf0 + n * 512);
    asm volatile("s_waitcnt vmcnt(8)" ::: "memory");
    __builtin_amdgcn_s_barrier();

    auto iter_body = [&](int it, short8 (&wtC)[4], short8 (&wtN)[4]){
        // A: DMA it+2 (newest; 2 iters of flight)
        if (it < 30) dma(it + 2);
        __builtin_amdgcn_sched_barrier(0);
        // B: wt prefetch for it+1
        if (it < 31){
            const ushort* wp = wtf0 + (size_t)(it + 1) * 16384;
            #pragma unroll
            for (int n = 0; n < 4; n++) wtN[n] = *(const short8*)(wp + n * 512);
        }
        __builtin_amdgcn_sched_barrier(0);
        // C: compute from ring buf[it%3]; compiler auto-waits wt(it) = vmcnt(8),
        //    which (in-order) also retires DMA(it+1).
        const char* ab = (const char*)&ebf[it % 3][0];
        #pragma unroll
        for (int m = 0; m < 4; m++){
            const char* rb = ab + arow[m] * 128;
            f32x4 lo = *(const f32x4*)(rb + (aqA[m]      ) * 16);
            f32x4 hi = *(const f32x4*)(rb + (aqA[m] ^ 1u ) * 16);
            short8 af;
            #pragma unroll
            for (int e = 0; e < 4; e++){
                af[e]     = (short)__builtin_bit_cast(ushort, __float2bfloat16(lo[e]));
                af[e + 4] = (short)__builtin_bit_cast(ushort, __float2bfloat16(hi[e]));
            }
            #pragma unroll
            for (int n = 0; n < 4; n++)
                acc[m][n] = __builtin_amdgcn_mfma_f32_16x16x32_bf16(af, wtC[n], acc[m][n], 0, 0, 0);
        }
        __builtin_amdgcn_sched_barrier(0);
        // D: counted wait (DMA(it+1) landed for ALL waves after the barrier; never 0)
        asm volatile("s_waitcnt vmcnt(8)" ::: "memory");
        __builtin_amdgcn_sched_barrier(0);
        __builtin_amdgcn_s_barrier();
    };

    #pragma unroll 2
    for (int ii = 0; ii < 16; ++ii){
        iter_body(2 * ii,     wtA, wtB);
        iter_body(2 * ii + 1, wtB, wtA);
    }

    // epilogue: +proj_dec, fast-tanh, v-dot, reduce over this block's 128 cols
    float pdc[4], vc[4];
    #pragma unroll
    for (int n = 0; n < 4; n++){
        int c = bn * 128 + wn * 64 + n * 16 + l15;
        float p = 0.f;
        #pragma unroll
        for (int kc = 0; kc < 4; kc++) p += pdp[(kc * NB + b) * NA + c];
        pdc[n] = p;
        vc[n] = v[c];
    }
    #pragma unroll
    for (int m = 0; m < 4; m++){
        #pragma unroll
        for (int j = 0; j < 4; j++){
            float s = 0.f;
            #pragma unroll
            for (int n = 0; n < 4; n++) s += tanh_fast(acc[m][n][j] + pdc[n]) * vc[n];
            s += __shfl_xor(s, 1);
            s += __shfl_xor(s, 2);
            s += __shfl_xor(s, 4);
            s += __shfl_xor(s, 8);
            if (l15 == 0) sc[wm * 64 + m * 16 + grp * 4 + j][wn] = s;
        }
    }
    __syncthreads();
    if (t < 128)
        scrp[(size_t)bn * (NB * NS) + m0 + t] = sc[t][0] + sc[t][1];
}

// ---- K3: masked softmax; sums the four N-quarter score partials ----
__global__ __launch_bounds__(256) void k_softmax(const float* __restrict__ scrp,
                                                 const int* __restrict__ mask,
                                                 float* __restrict__ weights){
    int b = blockIdx.x, t = threadIdx.x;
    __shared__ float red[8];
    float vals[16];
    float mx = -FLT_MAX;
    #pragma unroll
    for (int i = 0; i < 16; i++){
        int s = i * 256 + t;
        float x = scrp[b * NS + s]
                + scrp[(size_t)(NB * NS) + b * NS + s]
                + scrp[2 * (size_t)(NB * NS) + b * NS + s]
                + scrp[3 * (size_t)(NB * NS) + b * NS + s];
        x = (mask[b * NS + s] != 0) ? x : -FLT_MAX;
        vals[i] = x;
        mx = fmaxf(mx, x);
    }
    #pragma unroll
    for (int off = 32; off; off >>= 1) mx = fmaxf(mx, __shfl_xor(mx, off));
    int wv = t >> 6;
    if ((t & 63) == 0) red[wv] = mx;
    __syncthreads();
    mx = fmaxf(fmaxf(red[0], red[1]), fmaxf(red[2], red[3]));
    float sum = 0.f;
    #pragma unroll
    for (int i = 0; i < 16; i++){ vals[i] = __expf(vals[i] - mx); sum += vals[i]; }
    #pragma unroll
    for (int off = 32; off; off >>= 1) sum += __shfl_xor(sum, off);
    if ((t & 63) == 0) red[4 + wv] = sum;
    __syncthreads();
    sum = red[4] + red[5] + red[6] + red[7];
    float inv = 1.f / sum;
    #pragma unroll
    for (int i = 0; i < 16; i++) weights[b * NS + i * 256 + t] = vals[i] * inv;
}

// ---- K4: context partials over S-chunks ----
__global__ __launch_bounds__(1024) void k_context(const float* __restrict__ E,
                                                  const float* __restrict__ weights,
                                                  float* __restrict__ part){
    int b = blockIdx.x >> 3, ch = blockIdx.x & 7;
    int t = threadIdx.x;
    int h = t >> 8, tg = t & 255;
    __shared__ float wsm[512];
    __shared__ __align__(16) f32x4 red[4][256];
    if (t < 512) wsm[t] = weights[b * NS + ch * 512 + t];
    __syncthreads();
    const f32x4* Ep = (const f32x4*)(E + ((size_t)b * NS + ch * 512 + h * 128) * NE) + tg;
    f32x4 acc; acc[0]=0.f; acc[1]=0.f; acc[2]=0.f; acc[3]=0.f;
    #pragma unroll 4
    for (int s = 0; s < 128; s++){
        f32x4 e = Ep[(size_t)s * 256];
        float w = wsm[h * 128 + s];
        acc[0] += w * e[0]; acc[1] += w * e[1];
        acc[2] += w * e[2]; acc[3] += w * e[3];
    }
    red[h][tg] = acc;
    __syncthreads();
    if (h == 0){
        f32x4 a0 = red[0][tg], a1 = red[1][tg], a2 = red[2][tg], a3 = red[3][tg];
        f32x4 s;
        s[0] = a0[0]+a1[0]+a2[0]+a3[0];
        s[1] = a0[1]+a1[1]+a2[1]+a3[1];
        s[2] = a0[2]+a1[2]+a2[2]+a3[2];
        s[3] = a0[3]+a1[3]+a2[3]+a3[3];
        *(f32x4*)(part + ((size_t)(b * 8 + ch)) * NE + tg * 4) = s;
    }
}

// ---- K5: reduce context partials ----
__global__ __launch_bounds__(256) void k_reduce_ctx(const float* __restrict__ part,
                                                    float* __restrict__ ctx){
    int i = blockIdx.x * 256 + threadIdx.x;  // 32768
    int b = i >> 10, e = i & 1023;
    float s = 0.f;
    #pragma unroll
    for (int ch = 0; ch < 8; ch++) s += part[((size_t)(b * 8 + ch)) * NE + e];
    ctx[i] = s;
}

extern "C" void kernel_launch(void* const* d_in, const int* in_sizes, int n_in,
                              void* d_out, int out_size, void* d_ws, size_t ws_size,
                              hipStream_t stream){
    const float* dec  = (const float*)d_in[0];
    const float* E    = (const float*)d_in[1];
    const int*   mask = (const int*)d_in[2];
    const float* Wh   = (const float*)d_in[3];
    const float* Ws   = (const float*)d_in[4];
    const float* v    = (const float*)d_in[5];
    float* ctx = (float*)d_out;               // (32,1024)
    float* weights = (float*)d_out + NB * NE; // (32,4096)

    char* ws = (char*)d_ws;
    ushort* WTf  = (ushort*)ws;                                     // 1 MB (frag-order W_h)
    float*  part = (float*)ws;                                      // 1 MB ctx partials (after k_scores)
    float*  pdp  = (float*)(ws + (1 << 20));                        // 256 KB proj_dec partials
    float*  scrp = (float*)(ws + (1 << 20) + (256 << 10));          // 2 MB score partials (4 quarters)

    k_prep_wtf<<<2048, 256, 0, stream>>>(Wh, WTf);
    k_projdec<<<128, 512, 0, stream>>>(dec, Ws, pdp);
    k_scores<<<4096, 256, 0, stream>>>(E, WTf, pdp, v, scrp);
    k_softmax<<<32, 256, 0, stream>>>(scrp, mask, weights);
    k_context<<<256, 1024, 0, stream>>>(E, weights, part);
    k_reduce_ctx<<<128, 256, 0, stream>>>(part, ctx);
}

// Round 13
// 384.961 us; speedup vs baseline: 1.7696x; 1.0210x over previous
//
#include <hip/hip_runtime.h>
#include <hip/hip_bf16.h>
#include <float.h>
#include <math.h>

#define NB 32
#define NS 4096
#define NE 1024
#define ND 1024
#define NA 512

typedef __attribute__((ext_vector_type(4))) float f32x4;
typedef __attribute__((ext_vector_type(8))) short short8;

static __device__ __forceinline__ ushort f2bf(float f){
    union { float f; unsigned int u; } x; x.f = f;
    unsigned int u = x.u + 0x7fffu + ((x.u >> 16) & 1u);
    return (ushort)(u >> 16);
}

static __device__ __forceinline__ float tanh_fast(float x){
    float e = __expf(2.f * x);
    return 1.f - 2.f / (e + 1.f);
}

// ---- K1a: W_h (1024x512 f32) -> WTf bf16 in MFMA-fragment order ----
// WTf[((s*32 + ng)*64 + lane)*8 + e]  (s = k-slice of 32, ng = n-frag of 16 cols)
//   = Wh[k = s*32 + (lane>>4)*8 + e][col = ng*16 + (lane&15)]
__global__ __launch_bounds__(256) void k_prep_wtf(const float* __restrict__ Wh,
                                                  ushort* __restrict__ WTf){
    int i = blockIdx.x * 256 + threadIdx.x;   // 524288 outputs
    int e = i & 7;
    int lane = (i >> 3) & 63;
    int ng = (i >> 9) & 31;
    int s = i >> 14;
    int k = s * 32 + (lane >> 4) * 8 + e;
    int col = ng * 16 + (lane & 15);
    WTf[i] = f2bf(Wh[k * NA + col]);
}

// ---- K1b: proj_dec partials ----
__global__ __launch_bounds__(512) void k_projdec(const float* __restrict__ dec,
                                                 const float* __restrict__ Ws,
                                                 float* __restrict__ pdp){
    int b = blockIdx.x >> 2, kc = blockIdx.x & 3;
    int a = threadIdx.x;
    const float* dp = dec + b * ND + kc * 256;
    const float* wp = Ws + (size_t)(kc * 256) * NA + a;
    float acc = 0.f;
    #pragma unroll 4
    for (int k = 0; k < 256; k++) acc += dp[k] * wp[(size_t)k * NA];
    pdp[(kc * NB + b) * NA + a] = acc;
}

// ---- K2: fused scores GEMM (R9 structure + wt register prefetch).
// BM=128, BN=128 (bn quarter), BK=32, 4 waves (2x2), 256 thr.
// Per iter: stage_load(it+1) [oldest] -> wt(it+1) prefetch [newer] ->
// compute with wt(it) ALREADY IN REGS (no vmem wait before MFMA; only lgkm)
// -> stage_write (vmcnt(4): wt stays in flight) -> one barrier.
__global__ __launch_bounds__(256, 3) void k_scores(const float* __restrict__ E,
                                                   const ushort* __restrict__ WTf,
                                                   const float* __restrict__ pdp,
                                                   const float* __restrict__ v,
                                                   float* __restrict__ scrp){
    const int t = threadIdx.x;
    const int lane = t & 63, w = t >> 6;
    const int l15 = lane & 15, grp = lane >> 4;
    const int wm = w >> 1, wn = w & 1;

    // XCD-major mapping: 4096 blocks; 4 bn-quarters of one m-tile adjacent.
    const int bid = blockIdx.x;
    const int xcd = bid & 7, slot = bid >> 3;     // 512 slots per XCD
    const int mblk = xcd * 128 + (slot >> 2);     // 0..1023
    const int bn = slot & 3;                      // N-quarter
    const int m0 = mblk << 7;                     // 128-row base
    const int b = mblk >> 5;                      // batch

    __shared__ __align__(16) ushort bft[2][128 * 32];  // 2 x 8KB bf16 E-tiles (swizzled)
    __shared__ float sc[128][2];

    // staging: thread -> row sr = t>>1 (0..127), half = t&1 (16 floats)
    const int sr = t >> 1, half = t & 1;
    const float* gsrc = E + (size_t)(m0 + sr) * NE + half * 16;

    f32x4 acc[4][4];
    f32x4 zero; zero[0]=0.f; zero[1]=0.f; zero[2]=0.f; zero[3]=0.f;
    #pragma unroll
    for (int m = 0; m < 4; m++)
        #pragma unroll
        for (int n = 0; n < 4; n++) acc[m][n] = zero;

    f32x4 st[4];
    auto stage_load = [&](int it){
        const f32x4* p = (const f32x4*)(gsrc + it * 32);
        st[0] = p[0]; st[1] = p[1]; st[2] = p[2]; st[3] = p[3];
    };
    // per row: 32 f32 -> 4 bf16 segs of 16B; thread writes segs half*2, half*2+1
    auto stage_write = [&](int buf){
        short8 h0, h1;
        #pragma unroll
        for (int e = 0; e < 4; e++){
            h0[e]     = (short)__builtin_bit_cast(ushort, __float2bfloat16(st[0][e]));
            h0[e + 4] = (short)__builtin_bit_cast(ushort, __float2bfloat16(st[1][e]));
            h1[e]     = (short)__builtin_bit_cast(ushort, __float2bfloat16(st[2][e]));
            h1[e + 4] = (short)__builtin_bit_cast(ushort, __float2bfloat16(st[3][e]));
        }
        char* bb = (char*)&bft[buf][0];
        unsigned s0 = (unsigned)(half * 2);
        *(short8*)(bb + sr * 64 + (((s0    ) ^ (unsigned)(sr & 3)) << 4)) = h0;
        *(short8*)(bb + sr * 64 + (((s0 + 1) ^ (unsigned)(sr & 3)) << 4)) = h1;
    };

    // B-frag base: ng = bn*8 + wn*4 + n; slice s = it at +it*16384 ushorts
    const ushort* wtf0 = WTf + ((size_t)(bn * 8 + wn * 4) * 64 + lane) * 8;
    short8 wtA[4], wtB[4];

    // prologue: stage tile 0, load wt slice 0
    stage_load(0);
    stage_write(0);
    #pragma unroll
    for (int n = 0; n < 4; n++) wtA[n] = *(const short8*)(wtf0 + n * 512);
    asm volatile("s_waitcnt lgkmcnt(0)" ::: "memory");
    __builtin_amdgcn_s_barrier();

    auto body = [&](int it, short8 (&wtC)[4], short8 (&wtN)[4]){
        const int buf = it & 1;
        // 1) next-tile HBM loads (OLDEST this iter)
        if (it < 31) stage_load(it + 1);
        __builtin_amdgcn_sched_barrier(0);
        // 2) wt prefetch for it+1 (NEWER)
        if (it < 31){
            const ushort* wp = wtf0 + (size_t)(it + 1) * 16384;
            #pragma unroll
            for (int n = 0; n < 4; n++) wtN[n] = *(const short8*)(wp + n * 512);
        }
        __builtin_amdgcn_sched_barrier(0);
        // 3) compute: wtC already in regs -> MFMA waits only on ds_read (lgkm)
        const char* base = (const char*)&bft[buf][0];
        #pragma unroll
        for (int m = 0; m < 4; m++){
            const int r = wm * 64 + m * 16 + l15;
            short8 af = *(const short8*)(base + r * 64 + (((unsigned)grp ^ (unsigned)(r & 3)) << 4));
            #pragma unroll
            for (int n = 0; n < 4; n++)
                acc[m][n] = __builtin_amdgcn_mfma_f32_16x16x32_bf16(af, wtC[n], acc[m][n], 0, 0, 0);
        }
        __builtin_amdgcn_sched_barrier(0);
        // 4) cvt + ds_write next tile: compiler waits vmcnt(4) on st (wt in flight)
        if (it < 31) stage_write(buf ^ 1);
        asm volatile("s_waitcnt lgkmcnt(0)" ::: "memory");
        __builtin_amdgcn_s_barrier();
    };

    #pragma unroll 2
    for (int ii = 0; ii < 16; ++ii){
        body(2 * ii,     wtA, wtB);
        body(2 * ii + 1, wtB, wtA);
    }

    // epilogue: +proj_dec, fast-tanh, v-dot, reduce over this block's 128 cols
    float pdc[4], vc[4];
    #pragma unroll
    for (int n = 0; n < 4; n++){
        int c = bn * 128 + wn * 64 + n * 16 + l15;
        float p = 0.f;
        #pragma unroll
        for (int kc = 0; kc < 4; kc++) p += pdp[(kc * NB + b) * NA + c];
        pdc[n] = p;
        vc[n] = v[c];
    }
    #pragma unroll
    for (int m = 0; m < 4; m++){
        #pragma unroll
        for (int j = 0; j < 4; j++){
            float s = 0.f;
            #pragma unroll
            for (int n = 0; n < 4; n++) s += tanh_fast(acc[m][n][j] + pdc[n]) * vc[n];
            s += __shfl_xor(s, 1);
            s += __shfl_xor(s, 2);
            s += __shfl_xor(s, 4);
            s += __shfl_xor(s, 8);
            if (l15 == 0) sc[wm * 64 + m * 16 + grp * 4 + j][wn] = s;
        }
    }
    __syncthreads();
    if (t < 128)
        scrp[(size_t)bn * (NB * NS) + m0 + t] = sc[t][0] + sc[t][1];
}

// ---- K3: masked softmax; sums the four N-quarter score partials ----
__global__ __launch_bounds__(256) void k_softmax(const float* __restrict__ scrp,
                                                 const int* __restrict__ mask,
                                                 float* __restrict__ weights){
    int b = blockIdx.x, t = threadIdx.x;
    __shared__ float red[8];
    float vals[16];
    float mx = -FLT_MAX;
    #pragma unroll
    for (int i = 0; i < 16; i++){
        int s = i * 256 + t;
        float x = scrp[b * NS + s]
                + scrp[(size_t)(NB * NS) + b * NS + s]
                + scrp[2 * (size_t)(NB * NS) + b * NS + s]
                + scrp[3 * (size_t)(NB * NS) + b * NS + s];
        x = (mask[b * NS + s] != 0) ? x : -FLT_MAX;
        vals[i] = x;
        mx = fmaxf(mx, x);
    }
    #pragma unroll
    for (int off = 32; off; off >>= 1) mx = fmaxf(mx, __shfl_xor(mx, off));
    int wv = t >> 6;
    if ((t & 63) == 0) red[wv] = mx;
    __syncthreads();
    mx = fmaxf(fmaxf(red[0], red[1]), fmaxf(red[2], red[3]));
    float sum = 0.f;
    #pragma unroll
    for (int i = 0; i < 16; i++){ vals[i] = __expf(vals[i] - mx); sum += vals[i]; }
    #pragma unroll
    for (int off = 32; off; off >>= 1) sum += __shfl_xor(sum, off);
    if ((t & 63) == 0) red[4 + wv] = sum;
    __syncthreads();
    sum = red[4] + red[5] + red[6] + red[7];
    float inv = 1.f / sum;
    #pragma unroll
    for (int i = 0; i < 16; i++) weights[b * NS + i * 256 + t] = vals[i] * inv;
}

// ---- K4: context partials over S-chunks ----
__global__ __launch_bounds__(1024) void k_context(const float* __restrict__ E,
                                                  const float* __restrict__ weights,
                                                  float* __restrict__ part){
    int b = blockIdx.x >> 3, ch = blockIdx.x & 7;
    int t = threadIdx.x;
    int h = t >> 8, tg = t & 255;
    __shared__ float wsm[512];
    __shared__ __align__(16) f32x4 red[4][256];
    if (t < 512) wsm[t] = weights[b * NS + ch * 512 + t];
    __syncthreads();
    const f32x4* Ep = (const f32x4*)(E + ((size_t)b * NS + ch * 512 + h * 128) * NE) + tg;
    f32x4 acc; acc[0]=0.f; acc[1]=0.f; acc[2]=0.f; acc[3]=0.f;
    #pragma unroll 4
    for (int s = 0; s < 128; s++){
        f32x4 e = Ep[(size_t)s * 256];
        float w = wsm[h * 128 + s];
        acc[0] += w * e[0]; acc[1] += w * e[1];
        acc[2] += w * e[2]; acc[3] += w * e[3];
    }
    red[h][tg] = acc;
    __syncthreads();
    if (h == 0){
        f32x4 a0 = red[0][tg], a1 = red[1][tg], a2 = red[2][tg], a3 = red[3][tg];
        f32x4 s;
        s[0] = a0[0]+a1[0]+a2[0]+a3[0];
        s[1] = a0[1]+a1[1]+a2[1]+a3[1];
        s[2] = a0[2]+a1[2]+a2[2]+a3[2];
        s[3] = a0[3]+a1[3]+a2[3]+a3[3];
        *(f32x4*)(part + ((size_t)(b * 8 + ch)) * NE + tg * 4) = s;
    }
}

// ---- K5: reduce context partials ----
__global__ __launch_bounds__(256) void k_reduce_ctx(const float* __restrict__ part,
                                                    float* __restrict__ ctx){
    int i = blockIdx.x * 256 + threadIdx.x;  // 32768
    int b = i >> 10, e = i & 1023;
    float s = 0.f;
    #pragma unroll
    for (int ch = 0; ch < 8; ch++) s += part[((size_t)(b * 8 + ch)) * NE + e];
    ctx[i] = s;
}

extern "C" void kernel_launch(void* const* d_in, const int* in_sizes, int n_in,
                              void* d_out, int out_size, void* d_ws, size_t ws_size,
                              hipStream_t stream){
    const float* dec  = (const float*)d_in[0];
    const float* E    = (const float*)d_in[1];
    const int*   mask = (const int*)d_in[2];
    const float* Wh   = (const float*)d_in[3];
    const float* Ws   = (const float*)d_in[4];
    const float* v    = (const float*)d_in[5];
    float* ctx = (float*)d_out;               // (32,1024)
    float* weights = (float*)d_out + NB * NE; // (32,4096)

    char* ws = (char*)d_ws;
    ushort* WTf  = (ushort*)ws;                                     // 1 MB (frag-order W_h)
    float*  part = (float*)ws;                                      // 1 MB ctx partials (after k_scores)
    float*  pdp  = (float*)(ws + (1 << 20));                        // 256 KB proj_dec partials
    float*  scrp = (float*)(ws + (1 << 20) + (256 << 10));          // 2 MB score partials (4 quarters)

    k_prep_wtf<<<2048, 256, 0, stream>>>(Wh, WTf);
    k_projdec<<<128, 512, 0, stream>>>(dec, Ws, pdp);
    k_scores<<<4096, 256, 0, stream>>>(E, WTf, pdp, v, scrp);
    k_softmax<<<32, 256, 0, stream>>>(scrp, mask, weights);
    k_context<<<256, 1024, 0, stream>>>(E, weights, part);
    k_reduce_ctx<<<128, 256, 0, stream>>>(part, ctx);
}